// Round 13
// baseline (206.884 us; speedup 1.0000x reference)
//
#include <hip/hip_runtime.h>
#include <hip/hip_bf16.h>
#include <cstdint>

#define D_MODEL 1024
#define NHEADS 16
#define HDIM 64
#define SEQ 2048
#define NBATCH 2
#define BT (NBATCH * SEQ) /* 4096 */

typedef short bf16x8 __attribute__((ext_vector_type(8)));
typedef float f32x4 __attribute__((ext_vector_type(4)));
typedef unsigned short u16;
typedef unsigned int u32;

__device__ inline u16 f2bf(float f) {  // RNE
    union { float f; u32 u; } x;
    x.f = f;
    u32 r = (x.u + 0x7fffu + ((x.u >> 16) & 1u)) >> 16;
    return (u16)r;
}

__device__ inline u32 pack2bf(float a, float b) {  // lo=bf16(a), hi=bf16(b), RNE via HW pack
    union { __hip_bfloat162 h; u32 u; } c;
    c.h = __float22bfloat162_rn(float2{a, b});
    return c.u;
}

__device__ inline float bf2f(u16 v) {
    union { u32 u; float f; } x;
    x.u = ((u32)v) << 16;
    return x.f;
}

__device__ inline void async_copy16(const u16* g, u16* l) {
    __builtin_amdgcn_global_load_lds((const __attribute__((address_space(1))) void*)g,
                                     (__attribute__((address_space(3))) void*)l, 16, 0, 0);
}

// gfx950 cross-lane swaps (VALU pipe, not DS):
// v_permlane32_swap_b32: dst lanes 32-63 <-> src lanes 0-31
// v_permlane16_swap_b32: dst rows 1,3 (lanes 16-31,48-63) <-> src rows 0,2 (lanes 0-15,32-47)
__device__ inline void permswap32(u32& a, u32& b) {
    asm("v_permlane32_swap_b32 %0, %1" : "+v"(a), "+v"(b));
}
__device__ inline void permswap16(u32& a, u32& b) {
    asm("v_permlane16_swap_b32 %0, %1" : "+v"(a), "+v"(b));
}

// ---------------- prep: casts + rope cs table, one launch ----------------
#define X4 (BT * D_MODEL / 4)        /* 1048576 */
#define W4 (D_MODEL * D_MODEL / 4)   /* 262144  */
#define ROPE_N (SEQ * 32)            /* 65536: (t, dm) pairs */

__global__ void prep_kernel(const float* __restrict__ x,
                            const float* __restrict__ wq, const float* __restrict__ wk,
                            const float* __restrict__ wv, const float* __restrict__ wo,
                            u16* __restrict__ xb,
                            u16* __restrict__ dq, u16* __restrict__ dk,
                            u16* __restrict__ dv, u16* __restrict__ dow,
                            float2* __restrict__ csT) {
    int idx = blockIdx.x * blockDim.x + threadIdx.x;
    if (idx < X4) {
        float4 v = ((const float4*)x)[idx];
        ushort4 o;
        o.x = f2bf(v.x); o.y = f2bf(v.y); o.z = f2bf(v.z); o.w = f2bf(v.w);
        ((ushort4*)xb)[idx] = o;
    } else if (idx < X4 + 4 * W4) {
        int j = idx - X4;
        int w = j >> 18, i = j & (W4 - 1);
        const float* s = (w == 0) ? wq : (w == 1) ? wk : (w == 2) ? wv : wo;
        u16* d = (w == 0) ? dq : (w == 1) ? dk : (w == 2) ? dv : dow;
        float4 v = ((const float4*)s)[i];
        ushort4 o;
        o.x = f2bf(v.x); o.y = f2bf(v.y); o.z = f2bf(v.z); o.w = f2bf(v.w);
        ((ushort4*)d)[i] = o;
    } else {
        int j = idx - (X4 + 4 * W4);
        if (j < ROPE_N) {
            int t = j >> 5, dm = j & 31;
            float invf = exp2f(-(float)dm * (13.287712379549449f / 32.0f));
            float ang = (float)t * invf;
            float s, c;
            sincosf(ang, &s, &c);
            csT[t * 32 + dm] = float2{c, s};
        }
    }
}

// ---------------- m97-style GEMM core, BK=64 (two [128][32] sub-blocks) ----------------
// R13: K-step 32 -> 64. Each barrier-pair now covers 8 async copies + 32 MFMA (was 4+16),
// halving the count of exposed vmcnt(0) drains (the m97 structure's documented ~20% cost).
// Sub-block layout [ks][128][32] keeps staging/fragment addressing byte-identical per
// sub-block: no new bank-conflict behavior. LDS 32 KB (fits the existing 33.8 KB buffer).
__device__ inline void gemm_tile_core(const u16* __restrict__ A, const u16* __restrict__ Bw,
                                      int blkM, int blkN,
                                      u16* Asmem, u16* Bsmem, f32x4 acc[4][4]) {
    const int tid = threadIdx.x;
    const int lane = tid & 63;
    const int wave = tid >> 6;
    const int waveM = wave >> 1, waveN = wave & 1;
    const int quad = lane >> 4, l16 = lane & 15;

    const int srow = tid >> 2;
    const int scol = (tid & 3) << 3;
    const u16* Ag0 = A + (size_t)(blkM * 128 + srow) * D_MODEL + scol;
    const u16* Ag1 = Ag0 + (size_t)64 * D_MODEL;
    const u16* Bg0 = Bw + (size_t)(blkN * 128 + srow) * D_MODEL + scol;
    const u16* Bg1 = Bg0 + (size_t)64 * D_MODEL;
    u16* Al0 = Asmem + srow * 32 + scol;   // ks=1 at +4096
    u16* Al1 = Al0 + 64 * 32;
    u16* Bl0 = Bsmem + srow * 32 + scol;
    u16* Bl1 = Bl0 + 64 * 32;

    for (int k0 = 0; k0 < D_MODEL; k0 += 64) {
        __syncthreads();
        async_copy16(Ag0 + k0, Al0);
        async_copy16(Ag1 + k0, Al1);
        async_copy16(Bg0 + k0, Bl0);
        async_copy16(Bg1 + k0, Bl1);
        async_copy16(Ag0 + k0 + 32, Al0 + 4096);
        async_copy16(Ag1 + k0 + 32, Al1 + 4096);
        async_copy16(Bg0 + k0 + 32, Bl0 + 4096);
        async_copy16(Bg1 + k0 + 32, Bl1 + 4096);
        __syncthreads();
#pragma unroll
        for (int ks = 0; ks < 2; ++ks) {
            bf16x8 af[4], bfr[4];
#pragma unroll
            for (int mt = 0; mt < 4; ++mt)
                af[mt] = *(const bf16x8*)&Asmem[ks * 4096 + (waveM * 64 + mt * 16 + l16) * 32 + quad * 8];
#pragma unroll
            for (int nt = 0; nt < 4; ++nt)
                bfr[nt] = *(const bf16x8*)&Bsmem[ks * 4096 + (waveN * 64 + nt * 16 + l16) * 32 + quad * 8];
#pragma unroll
            for (int mt = 0; mt < 4; ++mt)
#pragma unroll
                for (int nt = 0; nt < 4; ++nt)
                    acc[mt][nt] = __builtin_amdgcn_mfma_f32_16x16x32_bf16(af[mt], bfr[nt], acc[mt][nt], 0, 0, 0);
        }
    }
}

// ---------------- fused QKV projection + bias + RoPE + layout ----------------
#define QSCALE 0.1803368801111204f /* (1/8) * log2(e) */
#define VPAD 132 /* vtile row stride in u16 */

__global__ __launch_bounds__(256) void gemm_qkv_kernel(
    const u16* __restrict__ xb,
    const u16* __restrict__ wqb, const u16* __restrict__ wkb, const u16* __restrict__ wvb,
    const float* __restrict__ bq, const float* __restrict__ bk, const float* __restrict__ bv,
    const float2* __restrict__ csT,
    u16* __restrict__ Qb, u16* __restrict__ Kb, u16* __restrict__ VTb) {
    __shared__ __align__(16) u16 smem[128 * VPAD];  // 16896 u16; K-loop uses 16384 (32 KB)
    u16* Asmem = smem;            // [2][64*2][32] = 8192 u16
    u16* Bsmem = smem + 8192;     // [2][64*2][32] = 8192 u16

    // hw flat id n = x + 32y + 256z; XCD ~ n%8. Relabel: ly=n%8, lx=(n/8)%32, lz=(n/8)/32.
    const int n = blockIdx.x + 32 * blockIdx.y + 256 * blockIdx.z;
    const int ly = n & 7;
    const int m = n >> 3;
    const int lx = m & 31;
    const int lz = m >> 5;

    const u16* Bw = (lz == 0) ? wqb : (lz == 1) ? wkb : wvb;
    const float* bias = (lz == 0) ? bq : (lz == 1) ? bk : bv;

    f32x4 acc[4][4];
#pragma unroll
    for (int mt = 0; mt < 4; ++mt)
#pragma unroll
        for (int nt = 0; nt < 4; ++nt)
            acc[mt][nt] = (f32x4){0.f, 0.f, 0.f, 0.f};

    gemm_tile_core(xb, Bw, lx, ly, Asmem, Bsmem, acc);

    const int tid = threadIdx.x;
    const int lane = tid & 63, wave = tid >> 6;
    const int waveM = wave >> 1, waveN = wave & 1;
    const int quad = lane >> 4, l16 = lane & 15;
    const int gm0 = lx * 128 + waveM * 64 + quad * 4;
    const int gn0 = ly * 128 + waveN * 64 + l16;

    float bvv[4];
#pragma unroll
    for (int nt = 0; nt < 4; ++nt) bvv[nt] = bias[gn0 + nt * 16];
#pragma unroll
    for (int mt = 0; mt < 4; ++mt)
#pragma unroll
        for (int nt = 0; nt < 4; ++nt)
#pragma unroll
            for (int r = 0; r < 4; ++r) acc[mt][nt][r] += bvv[nt];

    if (lz < 2) {
        // RoPE via complex rotation on (d, d+32) pairs; cs table shared by the pair.
        u16* dst = (lz == 0) ? Qb : Kb;
        const float post = (lz == 0) ? QSCALE : 1.0f;
        const int h = 2 * ly + waveN;  // head is wave-uniform
#pragma unroll
        for (int mt = 0; mt < 4; ++mt) {
#pragma unroll
            for (int r = 0; r < 4; ++r) {
                int gm = gm0 + mt * 16 + r;
                int t = gm & (SEQ - 1), b = gm >> 11;
                float2 cs0 = csT[t * 32 + l16];        // dm = l16   (pairs nt0/nt2)
                float2 cs1 = csT[t * 32 + 16 + l16];   // dm = l16+16 (pairs nt1/nt3)
                float a0 = acc[mt][0][r], a1 = acc[mt][1][r];
                float a2 = acc[mt][2][r], a3 = acc[mt][3][r];
                size_t base = ((size_t)(b * NHEADS + h) * SEQ + t) * HDIM;
                dst[base + l16]      = f2bf((a0 * cs0.x - a2 * cs0.y) * post);
                dst[base + l16 + 16] = f2bf((a1 * cs1.x - a3 * cs1.y) * post);
                dst[base + l16 + 32] = f2bf((a2 * cs0.x + a0 * cs0.y) * post);
                dst[base + l16 + 48] = f2bf((a3 * cs1.x + a1 * cs1.y) * post);
            }
        }
    } else {
        // V epilogue: transpose through LDS, then fully-coalesced stores to VTb[bh][d][t]
        __syncthreads();
#pragma unroll
        for (int mt = 0; mt < 4; ++mt) {
            int t_local = waveM * 64 + mt * 16 + quad * 4;
#pragma unroll
            for (int nt = 0; nt < 4; ++nt) {
                int n_local = waveN * 64 + nt * 16 + l16;
                uint2 w;
                w.x = pack2bf(acc[mt][nt][0], acc[mt][nt][1]);
                w.y = pack2bf(acc[mt][nt][2], acc[mt][nt][3]);
                *(uint2*)&smem[n_local * VPAD + t_local] = w;
            }
        }
        __syncthreads();
        const int row = tid >> 1;
        const int hc = (tid & 1) * 64;
        const int n_g = ly * 128 + row;
        const int h = n_g >> 6, d = n_g & 63;
        const int b = (lx * 128) >> 11;
        const int t0 = ((lx * 128) & (SEQ - 1)) + hc;
        u16* dst = &VTb[((size_t)(b * NHEADS + h) * HDIM + d) * SEQ + t0];
        const u16* src = &smem[row * VPAD + hc];
#pragma unroll
        for (int j = 0; j < 8; ++j)
            *(int4*)&dst[j * 8] = *(const int4*)&src[j * 8];
    }
}

// ---------------- flash attention: R3 structure + XCD-group block swizzle ----------
// R10: swizzle verified — FETCH 69.7 -> 12.4 MB (K/V now co-XCD L2-resident); timing
// neutral (latency already hidden by dbuf pipeline) but kept: free HBM-traffic cut.
#define LPAD 72  /* row stride in u16 */

__global__ __launch_bounds__(256, 2) void flash_kernel(
    const u16* __restrict__ Qb, const u16* __restrict__ Kb, const u16* __restrict__ VTb,
    u16* __restrict__ Po0, u16* __restrict__ Po1, float* __restrict__ Ls) {
    __shared__ __align__(16) u16 Ks[2][64 * LPAD];   // [buf][kk][d]  18.4 KB
    __shared__ __align__(16) u16 VTs[2][64 * LPAD];  // [buf][d][kk]  18.4 KB

    const int tid = threadIdx.x;
    const int wave = tid >> 6, lane = tid & 63;
    const int quad = lane >> 4, l16 = lane & 15;
    // XCD-group swizzle: flat = x + 8*bh + 256*hf; XCD ~ flat%8. Relabel so a
    // (bh,hf) group's 8 x-blocks all have flat%8 == g%8 (co-XCD).
    const int flat = blockIdx.x + 8 * blockIdx.y + 256 * blockIdx.z;
    const int xblk = flat >> 6;      // 0..7
    const int g = flat & 63;
    const int bh = g & 31;
    const int hf = g >> 5;
    const u16* Qh = Qb + (size_t)bh * SEQ * HDIM;
    const u16* Kh = Kb + ((size_t)bh * SEQ + hf * (SEQ / 2)) * HDIM;
    const u16* Vh = VTb + (size_t)bh * HDIM * SEQ + hf * (SEQ / 2);
    const int qblk = xblk * 256 + wave * 64;

    // Q B-frags (Q pre-scaled by 0.125*log2e): aq[nt2][ks], 64 q rows
    bf16x8 aq[4][2];
#pragma unroll
    for (int nt2 = 0; nt2 < 4; ++nt2)
#pragma unroll
        for (int ks = 0; ks < 2; ++ks)
            aq[nt2][ks] = *(const bf16x8*)&Qh[(qblk + nt2 * 16 + l16) * HDIM + ks * 32 + quad * 8];

    f32x4 o[4][4];
    float lsum[4] = {0.f, 0.f, 0.f, 0.f};
#pragma unroll
    for (int mt2 = 0; mt2 < 4; ++mt2)
#pragma unroll
        for (int nt = 0; nt < 4; ++nt) o[mt2][nt] = (f32x4){0.f, 0.f, 0.f, 0.f};

    // staging addressing: thread covers row lr, 2x16B chunks
    const int lr = tid >> 2;         // 0..63
    const int lc = (tid & 3) * 16;   // u16 col: 0,16,32,48
    const u16* Kg = Kh + (size_t)lr * HDIM + lc;  // + it*64*HDIM
    const u16* Vg = Vh + (size_t)lr * SEQ + lc;   // + it*64
    const int sidx = lr * LPAD + lc;

    // prologue: tile 0 -> buf0 (exposed latency, once); issue tile 1 -> regs
    uint4 ka, kc, va, vc;
    ka = *(const uint4*)&Kg[0];
    kc = *(const uint4*)&Kg[8];
    va = *(const uint4*)&Vg[0];
    vc = *(const uint4*)&Vg[8];
    *(uint4*)&Ks[0][sidx] = ka;
    *(uint4*)&Ks[0][sidx + 8] = kc;
    *(uint4*)&VTs[0][sidx] = va;
    *(uint4*)&VTs[0][sidx + 8] = vc;
    ka = *(const uint4*)&Kg[(size_t)64 * HDIM];
    kc = *(const uint4*)&Kg[(size_t)64 * HDIM + 8];
    va = *(const uint4*)&Vg[64];
    vc = *(const uint4*)&Vg[64 + 8];
    __syncthreads();

#pragma unroll 2
    for (int it = 0; it < 16; ++it) {
        const int cur = it & 1;
        // write tile it+1 into the buffer nobody reads this iteration
        if (it < 15) {
            *(uint4*)&Ks[cur ^ 1][sidx] = ka;
            *(uint4*)&Ks[cur ^ 1][sidx + 8] = kc;
            *(uint4*)&VTs[cur ^ 1][sidx] = va;
            *(uint4*)&VTs[cur ^ 1][sidx + 8] = vc;
        }
        // issue tile it+2 loads; they drain under this iteration's compute
        if (it < 14) {
            ka = *(const uint4*)&Kg[(size_t)(it + 2) * 64 * HDIM];
            kc = *(const uint4*)&Kg[(size_t)(it + 2) * 64 * HDIM + 8];
            va = *(const uint4*)&Vg[(it + 2) * 64];
            vc = *(const uint4*)&Vg[(it + 2) * 64 + 8];
        }
        const u16* Ksc = Ks[cur];
        const u16* Vsc = VTs[cur];

        // S^T[kk][q] = K·Q^T : per wave 64kk x 64q. C/D: col(l16)=q, row(quad*4+r)=kk
        f32x4 sacc[4][4];
#pragma unroll
        for (int mt = 0; mt < 4; ++mt)
#pragma unroll
            for (int nt2 = 0; nt2 < 4; ++nt2) sacc[mt][nt2] = (f32x4){0.f, 0.f, 0.f, 0.f};
#pragma unroll
        for (int ks = 0; ks < 2; ++ks) {
            bf16x8 kf[4];
#pragma unroll
            for (int mt = 0; mt < 4; ++mt)
                kf[mt] = *(const bf16x8*)&Ksc[(mt * 16 + l16) * LPAD + ks * 32 + quad * 8];
#pragma unroll
            for (int mt = 0; mt < 4; ++mt)
#pragma unroll
                for (int nt2 = 0; nt2 < 4; ++nt2)
                    sacc[mt][nt2] = __builtin_amdgcn_mfma_f32_16x16x32_bf16(kf[mt], aq[nt2][ks], sacc[mt][nt2], 0, 0, 0);
        }

        // P = exp2(S) -> bf16 pairs -> quad exchange in-register (VALU, no LDS).
        u32 pq[4][2][4];  // [nt2][ks][c]
#pragma unroll
        for (int nt2 = 0; nt2 < 4; ++nt2) {
            u32 w[4][2];
#pragma unroll
            for (int mt = 0; mt < 4; ++mt) {
                float p0 = __builtin_amdgcn_exp2f(sacc[mt][nt2][0]);
                float p1 = __builtin_amdgcn_exp2f(sacc[mt][nt2][1]);
                float p2 = __builtin_amdgcn_exp2f(sacc[mt][nt2][2]);
                float p3 = __builtin_amdgcn_exp2f(sacc[mt][nt2][3]);
                lsum[nt2] += (p0 + p1) + (p2 + p3);
                w[mt][0] = pack2bf(p0, p1);
                w[mt][1] = pack2bf(p2, p3);
            }
#pragma unroll
            for (int ks = 0; ks < 2; ++ks)
#pragma unroll
                for (int h = 0; h < 2; ++h) {
                    u32 a = w[2 * ks][h], b = w[2 * ks + 1][h];
                    permswap32(a, b);
                    permswap16(a, b);
                    pq[nt2][ks][h] = a;
                    pq[nt2][ks][2 + h] = b;
                }
        }

        // O += P·V : A=P frags (in-register), B=V[d][kk] frags from LDS
#pragma unroll
        for (int ks = 0; ks < 2; ++ks) {
            bf16x8 vf[4];
#pragma unroll
            for (int nt = 0; nt < 4; ++nt)
                vf[nt] = *(const bf16x8*)&Vsc[(nt * 16 + l16) * LPAD + ks * 32 + quad * 8];
#pragma unroll
            for (int mt2 = 0; mt2 < 4; ++mt2) {
                union { u32 u[4]; bf16x8 v; } pf;
                pf.u[0] = pq[mt2][ks][0];
                pf.u[1] = pq[mt2][ks][1];
                pf.u[2] = pq[mt2][ks][2];
                pf.u[3] = pq[mt2][ks][3];
#pragma unroll
                for (int nt = 0; nt < 4; ++nt)
                    o[mt2][nt] = __builtin_amdgcn_mfma_f32_16x16x32_bf16(pf.v, vf[nt], o[mt2][nt], 0, 0, 0);
            }
        }
        // single barrier: separates this iter's buf[cur] reads from next iter's writes,
        // and this iter's buf[cur^1] writes from next iter's reads.
        __syncthreads();
    }

    // complete row sums over the 4 quads (disjoint kk): lane l16 then holds q = nt2*16+l16
#pragma unroll
    for (int nt2 = 0; nt2 < 4; ++nt2) {
        lsum[nt2] += __shfl_xor(lsum[nt2], 16, 64);
        lsum[nt2] += __shfl_xor(lsum[nt2], 32, 64);
    }

    // epilogue: write UNNORMALIZED partial O (bf16) + row sums; gemm_out normalizes.
    const int b = bh >> 4, h = bh & 15;
    u16* dst = hf ? Po1 : Po0;
#pragma unroll
    for (int mt2 = 0; mt2 < 4; ++mt2) {
#pragma unroll
        for (int nt = 0; nt < 4; ++nt) {
            int d = nt * 16 + l16;
#pragma unroll
            for (int r = 0; r < 4; ++r) {
                int q = qblk + mt2 * 16 + quad * 4 + r;
                dst[((size_t)(b * SEQ + q)) * D_MODEL + h * HDIM + d] = f2bf(o[mt2][nt][r]);
            }
        }
    }
    if (quad == 0) {
#pragma unroll
        for (int nt2 = 0; nt2 < 4; ++nt2) {
            int q = qblk + nt2 * 16 + l16;
            Ls[hf * (32 * SEQ) + bh * SEQ + q] = lsum[nt2];
        }
    }
}

// ---------------- output projection: fused combine, BK=64 sub-blocks + XCD swizzle ----
// Same drain-halving as gemm_qkv: 16 K-iters (was 32), each staging 2x A-combine writes
// + 4 B-async and computing 16 MFMA. LDS 24 KB.
__global__ __launch_bounds__(256) void gemm_out_kernel(
    const u16* __restrict__ Po0, const u16* __restrict__ Po1, const float* __restrict__ Ls,
    const u16* __restrict__ wob, const float* __restrict__ bo, float* __restrict__ dout) {
    __shared__ __align__(16) u16 Asmem[2 * 64 * 32];   // [ks][64][32]
    __shared__ __align__(16) u16 Bsmem[2 * 128 * 32];  // [ks][128][32]

    const int tid = threadIdx.x;
    const int lane = tid & 63, wave = tid >> 6;
    const int waveM = wave >> 1, waveN = wave & 1;
    const int quad = lane >> 4, l16 = lane & 15;

    const int n = blockIdx.x + 64 * blockIdx.y;
    const int ly = n & 7;
    const int lx = n >> 3;

    f32x4 acc[2][4];
#pragma unroll
    for (int mt = 0; mt < 2; ++mt)
#pragma unroll
        for (int nt = 0; nt < 4; ++nt) acc[mt][nt] = (f32x4){0.f, 0.f, 0.f, 0.f};

    const int srow = tid >> 2;
    const int scol = (tid & 3) << 3;
    const int q = lx * 64 + srow;
    const int b = q >> 11, t = q & (SEQ - 1);
    const size_t arow = (size_t)q * D_MODEL + scol;
    const u16* Bg0 = wob + (size_t)(ly * 128 + srow) * D_MODEL + scol;
    const u16* Bg1 = Bg0 + (size_t)64 * D_MODEL;
    u16* Al = Asmem + srow * 32 + scol;              // ks=1 at +2048
    u16* Bl0 = Bsmem + srow * 32 + scol;             // ks=1 at +4096
    u16* Bl1 = Bl0 + 64 * 32;

    // precompute 1/l per head for this thread's row
    float rinvh[NHEADS];
    {
        const int bhq0 = b * NHEADS * SEQ + t;
#pragma unroll
        for (int h = 0; h < NHEADS; ++h) {
            int bhq = bhq0 + h * SEQ;
            rinvh[h] = 1.0f / (Ls[bhq] + Ls[32 * SEQ + bhq]);
        }
    }

    // prefetch iter 0's A rows (k0 and k0+32 slices of Po0/Po1)
    uint4 A0 = *(const uint4*)&Po0[arow];
    uint4 A1 = *(const uint4*)&Po1[arow];
    uint4 A2 = *(const uint4*)&Po0[arow + 32];
    uint4 A3 = *(const uint4*)&Po1[arow + 32];

    for (int k0 = 0; k0 < D_MODEL; k0 += 64) {
        __syncthreads();
        // A path: fused (Po0+Po1)*rinv -> bf16 -> LDS, both 32-col slices.
        // k0 is 64-aligned and scol<32, so both slices share one head -> one rinv.
        float rinv = rinvh[k0 >> 6];
        {
            const u16* p0 = (const u16*)&A0;
            const u16* p1 = (const u16*)&A1;
            uint4 wv;
            u32* wvp = (u32*)&wv;
#pragma unroll
            for (int j = 0; j < 4; ++j) {
                float s0 = (bf2f(p0[2 * j]) + bf2f(p1[2 * j])) * rinv;
                float s1 = (bf2f(p0[2 * j + 1]) + bf2f(p1[2 * j + 1])) * rinv;
                wvp[j] = pack2bf(s0, s1);
            }
            *(uint4*)Al = wv;
        }
        {
            const u16* p2 = (const u16*)&A2;
            const u16* p3 = (const u16*)&A3;
            uint4 wv;
            u32* wvp = (u32*)&wv;
#pragma unroll
            for (int j = 0; j < 4; ++j) {
                float s0 = (bf2f(p2[2 * j]) + bf2f(p3[2 * j])) * rinv;
                float s1 = (bf2f(p2[2 * j + 1]) + bf2f(p3[2 * j + 1])) * rinv;
                wvp[j] = pack2bf(s0, s1);
            }
            *(uint4*)(Al + 2048) = wv;
        }
        // B path: async global->LDS, both 32-col slices
        async_copy16(Bg0 + k0, Bl0);
        async_copy16(Bg1 + k0, Bl1);
        async_copy16(Bg0 + k0 + 32, Bl0 + 4096);
        async_copy16(Bg1 + k0 + 32, Bl1 + 4096);
        // prefetch next iter's A rows; latency drains with the barrier's vmcnt wait
        if (k0 + 64 < D_MODEL) {
            A0 = *(const uint4*)&Po0[arow + k0 + 64];
            A1 = *(const uint4*)&Po1[arow + k0 + 64];
            A2 = *(const uint4*)&Po0[arow + k0 + 96];
            A3 = *(const uint4*)&Po1[arow + k0 + 96];
        }
        __syncthreads();
#pragma unroll
        for (int ks = 0; ks < 2; ++ks) {
            bf16x8 af[2], bfr[4];
#pragma unroll
            for (int mt = 0; mt < 2; ++mt)
                af[mt] = *(const bf16x8*)&Asmem[ks * 2048 + (waveM * 32 + mt * 16 + l16) * 32 + quad * 8];
#pragma unroll
            for (int nt = 0; nt < 4; ++nt)
                bfr[nt] = *(const bf16x8*)&Bsmem[ks * 4096 + (waveN * 64 + nt * 16 + l16) * 32 + quad * 8];
#pragma unroll
            for (int mt = 0; mt < 2; ++mt)
#pragma unroll
                for (int nt = 0; nt < 4; ++nt)
                    acc[mt][nt] = __builtin_amdgcn_mfma_f32_16x16x32_bf16(af[mt], bfr[nt], acc[mt][nt], 0, 0, 0);
        }
    }

    const int gm0 = lx * 64 + waveM * 32 + quad * 4;
    const int gn0 = ly * 128 + waveN * 64 + l16;

    float bvv[4];
#pragma unroll
    for (int nt = 0; nt < 4; ++nt) bvv[nt] = bo[gn0 + nt * 16];
#pragma unroll
    for (int mt = 0; mt < 2; ++mt)
#pragma unroll
        for (int nt = 0; nt < 4; ++nt)
#pragma unroll
            for (int r = 0; r < 4; ++r)
                dout[(size_t)(gm0 + mt * 16 + r) * D_MODEL + gn0 + nt * 16] = acc[mt][nt][r] + bvv[nt];
}

// ---------------- launch ----------------
extern "C" void kernel_launch(void* const* d_in, const int* in_sizes, int n_in,
                              void* d_out, int out_size, void* d_ws, size_t ws_size,
                              hipStream_t stream) {
    const float* x  = (const float*)d_in[0];
    const float* Wq = (const float*)d_in[1];
    const float* bq = (const float*)d_in[2];
    const float* Wk = (const float*)d_in[3];
    const float* bk = (const float*)d_in[4];
    const float* Wv = (const float*)d_in[5];
    const float* bv = (const float*)d_in[6];
    const float* Wo = (const float*)d_in[7];
    const float* bo = (const float*)d_in[8];
    float* dout = (float*)d_out;

    char* ws = (char*)d_ws;
    size_t off = 0;
    u16* xb  = (u16*)(ws + off); off += (size_t)BT * D_MODEL * 2;        // 8 MB; reused as Po1
    u16* wqb = (u16*)(ws + off); off += (size_t)D_MODEL * D_MODEL * 2;
    u16* wkb = (u16*)(ws + off); off += (size_t)D_MODEL * D_MODEL * 2;
    u16* wvb = (u16*)(ws + off); off += (size_t)D_MODEL * D_MODEL * 2;
    u16* wob = (u16*)(ws + off); off += (size_t)D_MODEL * D_MODEL * 2;
    u16* Qb  = (u16*)(ws + off); off += (size_t)BT * D_MODEL * 2;
    u16* Kb  = (u16*)(ws + off); off += (size_t)BT * D_MODEL * 2;
    u16* VTb = (u16*)(ws + off); off += (size_t)BT * D_MODEL * 2;
    u16* Po0 = (u16*)(ws + off); off += (size_t)BT * D_MODEL * 2;
    float2* csT = (float2*)(ws + off); off += (size_t)SEQ * 32 * 8;      // 0.5 MB
    float* Ls   = (float*)(ws + off); off += (size_t)2 * 32 * SEQ * 4;   // 0.5 MB
    u16* Po1 = xb;  // alias: xb is dead after gemm_qkv

    const int prepN = X4 + 4 * W4 + ROPE_N;
    prep_kernel<<<dim3((prepN + 255) / 256), 256, 0, stream>>>(
        x, Wq, Wk, Wv, Wo, xb, wqb, wkb, wvb, wob, csT);
    gemm_qkv_kernel<<<dim3(BT / 128, D_MODEL / 128, 3), 256, 0, stream>>>(
        xb, wqb, wkb, wvb, bq, bk, bv, csT, Qb, Kb, VTb);
    flash_kernel<<<dim3(SEQ / 256, NBATCH * NHEADS, 2), 256, 0, stream>>>(
        Qb, Kb, VTb, Po0, Po1, Ls);
    gemm_out_kernel<<<dim3(BT / 64, D_MODEL / 128), 256, 0, stream>>>(
        Po0, Po1, Ls, wob, bo, dout);
}

// Round 14
// 198.459 us; speedup vs baseline: 1.0425x; 1.0425x over previous
//
#include <hip/hip_runtime.h>
#include <hip/hip_bf16.h>
#include <cstdint>

#define D_MODEL 1024
#define NHEADS 16
#define HDIM 64
#define SEQ 2048
#define NBATCH 2
#define BT (NBATCH * SEQ) /* 4096 */

typedef short bf16x8 __attribute__((ext_vector_type(8)));
typedef float f32x4 __attribute__((ext_vector_type(4)));
typedef unsigned short u16;
typedef unsigned int u32;

__device__ inline u16 f2bf(float f) {  // RNE
    union { float f; u32 u; } x;
    x.f = f;
    u32 r = (x.u + 0x7fffu + ((x.u >> 16) & 1u)) >> 16;
    return (u16)r;
}

__device__ inline u32 pack2bf(float a, float b) {  // lo=bf16(a), hi=bf16(b), RNE via HW pack
    union { __hip_bfloat162 h; u32 u; } c;
    c.h = __float22bfloat162_rn(float2{a, b});
    return c.u;
}

__device__ inline float bf2f(u16 v) {
    union { u32 u; float f; } x;
    x.u = ((u32)v) << 16;
    return x.f;
}

__device__ inline void async_copy16(const u16* g, u16* l) {
    __builtin_amdgcn_global_load_lds((const __attribute__((address_space(1))) void*)g,
                                     (__attribute__((address_space(3))) void*)l, 16, 0, 0);
}

// gfx950 cross-lane swaps (VALU pipe, not DS):
// v_permlane32_swap_b32: dst lanes 32-63 <-> src lanes 0-31
// v_permlane16_swap_b32: dst rows 1,3 (lanes 16-31,48-63) <-> src rows 0,2 (lanes 0-15,32-47)
__device__ inline void permswap32(u32& a, u32& b) {
    asm("v_permlane32_swap_b32 %0, %1" : "+v"(a), "+v"(b));
}
__device__ inline void permswap16(u32& a, u32& b) {
    asm("v_permlane16_swap_b32 %0, %1" : "+v"(a), "+v"(b));
}

// ---------------- prep: casts + rope cs table, one launch ----------------
#define X4 (BT * D_MODEL / 4)        /* 1048576 */
#define W4 (D_MODEL * D_MODEL / 4)   /* 262144  */
#define ROPE_N (SEQ * 32)            /* 65536: (t, dm) pairs */

__global__ void prep_kernel(const float* __restrict__ x,
                            const float* __restrict__ wq, const float* __restrict__ wk,
                            const float* __restrict__ wv, const float* __restrict__ wo,
                            u16* __restrict__ xb,
                            u16* __restrict__ dq, u16* __restrict__ dk,
                            u16* __restrict__ dv, u16* __restrict__ dow,
                            float2* __restrict__ csT) {
    int idx = blockIdx.x * blockDim.x + threadIdx.x;
    if (idx < X4) {
        float4 v = ((const float4*)x)[idx];
        ushort4 o;
        o.x = f2bf(v.x); o.y = f2bf(v.y); o.z = f2bf(v.z); o.w = f2bf(v.w);
        ((ushort4*)xb)[idx] = o;
    } else if (idx < X4 + 4 * W4) {
        int j = idx - X4;
        int w = j >> 18, i = j & (W4 - 1);
        const float* s = (w == 0) ? wq : (w == 1) ? wk : (w == 2) ? wv : wo;
        u16* d = (w == 0) ? dq : (w == 1) ? dk : (w == 2) ? dv : dow;
        float4 v = ((const float4*)s)[i];
        ushort4 o;
        o.x = f2bf(v.x); o.y = f2bf(v.y); o.z = f2bf(v.z); o.w = f2bf(v.w);
        ((ushort4*)d)[i] = o;
    } else {
        int j = idx - (X4 + 4 * W4);
        if (j < ROPE_N) {
            int t = j >> 5, dm = j & 31;
            float invf = exp2f(-(float)dm * (13.287712379549449f / 32.0f));
            float ang = (float)t * invf;
            float s, c;
            sincosf(ang, &s, &c);
            csT[t * 32 + dm] = float2{c, s};
        }
    }
}

// ---------------- m97-style GEMM core (128x128 tile, BK=32) ----------------
// Measured-best for this tile size. R7 (reg-staged 1-barrier) neutral; R8 (fp32-A mix)
// -26us; R13 (BK=64) -6us: the single short drain + frequent barriers maximizes the
// implicit cross-block wave overlap (m114) that does the latency hiding here.
__device__ inline void gemm_tile_core(const u16* __restrict__ A, const u16* __restrict__ Bw,
                                      int blkM, int blkN,
                                      u16* Asmem, u16* Bsmem, f32x4 acc[4][4]) {
    const int tid = threadIdx.x;
    const int lane = tid & 63;
    const int wave = tid >> 6;
    const int waveM = wave >> 1, waveN = wave & 1;
    const int quad = lane >> 4, l16 = lane & 15;

    const int srow = tid >> 2;
    const int scol = (tid & 3) << 3;
    const u16* Ag0 = A + (size_t)(blkM * 128 + srow) * D_MODEL + scol;
    const u16* Ag1 = Ag0 + (size_t)64 * D_MODEL;
    const u16* Bg0 = Bw + (size_t)(blkN * 128 + srow) * D_MODEL + scol;
    const u16* Bg1 = Bg0 + (size_t)64 * D_MODEL;
    u16* Al0 = Asmem + srow * 32 + scol;
    u16* Al1 = Al0 + 64 * 32;
    u16* Bl0 = Bsmem + srow * 32 + scol;
    u16* Bl1 = Bl0 + 64 * 32;

    for (int k0 = 0; k0 < D_MODEL; k0 += 32) {
        __syncthreads();
        async_copy16(Ag0 + k0, Al0);
        async_copy16(Ag1 + k0, Al1);
        async_copy16(Bg0 + k0, Bl0);
        async_copy16(Bg1 + k0, Bl1);
        __syncthreads();
        bf16x8 af[4], bfr[4];
#pragma unroll
        for (int mt = 0; mt < 4; ++mt)
            af[mt] = *(const bf16x8*)&Asmem[(waveM * 64 + mt * 16 + l16) * 32 + quad * 8];
#pragma unroll
        for (int nt = 0; nt < 4; ++nt)
            bfr[nt] = *(const bf16x8*)&Bsmem[(waveN * 64 + nt * 16 + l16) * 32 + quad * 8];
#pragma unroll
        for (int mt = 0; mt < 4; ++mt)
#pragma unroll
            for (int nt = 0; nt < 4; ++nt)
                acc[mt][nt] = __builtin_amdgcn_mfma_f32_16x16x32_bf16(af[mt], bfr[nt], acc[mt][nt], 0, 0, 0);
    }
}

// ---------------- fused QKV projection + bias + RoPE + layout ----------------
#define QSCALE 0.1803368801111204f /* (1/8) * log2(e) */
#define VPAD 132 /* vtile row stride in u16 */

__global__ __launch_bounds__(256) void gemm_qkv_kernel(
    const u16* __restrict__ xb,
    const u16* __restrict__ wqb, const u16* __restrict__ wkb, const u16* __restrict__ wvb,
    const float* __restrict__ bq, const float* __restrict__ bk, const float* __restrict__ bv,
    const float2* __restrict__ csT,
    u16* __restrict__ Qb, u16* __restrict__ Kb, u16* __restrict__ VTb) {
    __shared__ __align__(16) u16 smem[128 * VPAD];
    u16* Asmem = smem;
    u16* Bsmem = smem + 128 * 32;

    const int z = blockIdx.z;
    const u16* Bw = (z == 0) ? wqb : (z == 1) ? wkb : wvb;
    const float* bias = (z == 0) ? bq : (z == 1) ? bk : bv;

    f32x4 acc[4][4];
#pragma unroll
    for (int mt = 0; mt < 4; ++mt)
#pragma unroll
        for (int nt = 0; nt < 4; ++nt)
            acc[mt][nt] = (f32x4){0.f, 0.f, 0.f, 0.f};

    gemm_tile_core(xb, Bw, blockIdx.x, blockIdx.y, Asmem, Bsmem, acc);

    const int tid = threadIdx.x;
    const int lane = tid & 63, wave = tid >> 6;
    const int waveM = wave >> 1, waveN = wave & 1;
    const int quad = lane >> 4, l16 = lane & 15;
    const int gm0 = blockIdx.x * 128 + waveM * 64 + quad * 4;
    const int gn0 = blockIdx.y * 128 + waveN * 64 + l16;

    float bvv[4];
#pragma unroll
    for (int nt = 0; nt < 4; ++nt) bvv[nt] = bias[gn0 + nt * 16];
#pragma unroll
    for (int mt = 0; mt < 4; ++mt)
#pragma unroll
        for (int nt = 0; nt < 4; ++nt)
#pragma unroll
            for (int r = 0; r < 4; ++r) acc[mt][nt][r] += bvv[nt];

    if (z < 2) {
        // RoPE via complex rotation on (d, d+32) pairs; cs table shared by the pair.
        u16* dst = (z == 0) ? Qb : Kb;
        const float post = (z == 0) ? QSCALE : 1.0f;
        const int h = 2 * blockIdx.y + waveN;  // head is wave-uniform
#pragma unroll
        for (int mt = 0; mt < 4; ++mt) {
#pragma unroll
            for (int r = 0; r < 4; ++r) {
                int gm = gm0 + mt * 16 + r;
                int t = gm & (SEQ - 1), b = gm >> 11;
                float2 cs0 = csT[t * 32 + l16];        // dm = l16   (pairs nt0/nt2)
                float2 cs1 = csT[t * 32 + 16 + l16];   // dm = l16+16 (pairs nt1/nt3)
                float a0 = acc[mt][0][r], a1 = acc[mt][1][r];
                float a2 = acc[mt][2][r], a3 = acc[mt][3][r];
                size_t base = ((size_t)(b * NHEADS + h) * SEQ + t) * HDIM;
                dst[base + l16]      = f2bf((a0 * cs0.x - a2 * cs0.y) * post);
                dst[base + l16 + 16] = f2bf((a1 * cs1.x - a3 * cs1.y) * post);
                dst[base + l16 + 32] = f2bf((a2 * cs0.x + a0 * cs0.y) * post);
                dst[base + l16 + 48] = f2bf((a3 * cs1.x + a1 * cs1.y) * post);
            }
        }
    } else {
        // V epilogue: transpose through LDS, then fully-coalesced stores to VTb[bh][d][t]
        __syncthreads();
#pragma unroll
        for (int mt = 0; mt < 4; ++mt) {
            int t_local = waveM * 64 + mt * 16 + quad * 4;
#pragma unroll
            for (int nt = 0; nt < 4; ++nt) {
                int n_local = waveN * 64 + nt * 16 + l16;
                uint2 w;
                w.x = pack2bf(acc[mt][nt][0], acc[mt][nt][1]);
                w.y = pack2bf(acc[mt][nt][2], acc[mt][nt][3]);
                *(uint2*)&smem[n_local * VPAD + t_local] = w;
            }
        }
        __syncthreads();
        const int row = tid >> 1;
        const int hc = (tid & 1) * 64;
        const int n_g = blockIdx.y * 128 + row;
        const int h = n_g >> 6, d = n_g & 63;
        const int b = (blockIdx.x * 128) >> 11;
        const int t0 = ((blockIdx.x * 128) & (SEQ - 1)) + hc;
        u16* dst = &VTb[((size_t)(b * NHEADS + h) * HDIM + d) * SEQ + t0];
        const u16* src = &smem[row * VPAD + hc];
#pragma unroll
        for (int j = 0; j < 8; ++j)
            *(int4*)&dst[j * 8] = *(const int4*)&src[j * 8];
    }
}

// ---------------- flash attention: R3 structure + XCD-group block swizzle ----------
// R10: swizzle verified — FETCH 69.7 -> 12.4 MB (K/V now co-XCD L2-resident); timing
// neutral (latency already hidden by dbuf pipeline) but kept: free HBM-traffic cut.
#define LPAD 72  /* row stride in u16 */

__global__ __launch_bounds__(256, 2) void flash_kernel(
    const u16* __restrict__ Qb, const u16* __restrict__ Kb, const u16* __restrict__ VTb,
    u16* __restrict__ Po0, u16* __restrict__ Po1, float* __restrict__ Ls) {
    __shared__ __align__(16) u16 Ks[2][64 * LPAD];   // [buf][kk][d]  18.4 KB
    __shared__ __align__(16) u16 VTs[2][64 * LPAD];  // [buf][d][kk]  18.4 KB

    const int tid = threadIdx.x;
    const int wave = tid >> 6, lane = tid & 63;
    const int quad = lane >> 4, l16 = lane & 15;
    // XCD-group swizzle: flat = x + 8*bh + 256*hf; XCD ~ flat%8. Relabel so a
    // (bh,hf) group's 8 x-blocks all have flat%8 == g%8 (co-XCD).
    const int flat = blockIdx.x + 8 * blockIdx.y + 256 * blockIdx.z;
    const int xblk = flat >> 6;      // 0..7
    const int g = flat & 63;
    const int bh = g & 31;
    const int hf = g >> 5;
    const u16* Qh = Qb + (size_t)bh * SEQ * HDIM;
    const u16* Kh = Kb + ((size_t)bh * SEQ + hf * (SEQ / 2)) * HDIM;
    const u16* Vh = VTb + (size_t)bh * HDIM * SEQ + hf * (SEQ / 2);
    const int qblk = xblk * 256 + wave * 64;

    // Q B-frags (Q pre-scaled by 0.125*log2e): aq[nt2][ks], 64 q rows
    bf16x8 aq[4][2];
#pragma unroll
    for (int nt2 = 0; nt2 < 4; ++nt2)
#pragma unroll
        for (int ks = 0; ks < 2; ++ks)
            aq[nt2][ks] = *(const bf16x8*)&Qh[(qblk + nt2 * 16 + l16) * HDIM + ks * 32 + quad * 8];

    f32x4 o[4][4];
    float lsum[4] = {0.f, 0.f, 0.f, 0.f};
#pragma unroll
    for (int mt2 = 0; mt2 < 4; ++mt2)
#pragma unroll
        for (int nt = 0; nt < 4; ++nt) o[mt2][nt] = (f32x4){0.f, 0.f, 0.f, 0.f};

    // staging addressing: thread covers row lr, 2x16B chunks
    const int lr = tid >> 2;         // 0..63
    const int lc = (tid & 3) * 16;   // u16 col: 0,16,32,48
    const u16* Kg = Kh + (size_t)lr * HDIM + lc;  // + it*64*HDIM
    const u16* Vg = Vh + (size_t)lr * SEQ + lc;   // + it*64
    const int sidx = lr * LPAD + lc;

    // prologue: tile 0 -> buf0 (exposed latency, once); issue tile 1 -> regs
    uint4 ka, kc, va, vc;
    ka = *(const uint4*)&Kg[0];
    kc = *(const uint4*)&Kg[8];
    va = *(const uint4*)&Vg[0];
    vc = *(const uint4*)&Vg[8];
    *(uint4*)&Ks[0][sidx] = ka;
    *(uint4*)&Ks[0][sidx + 8] = kc;
    *(uint4*)&VTs[0][sidx] = va;
    *(uint4*)&VTs[0][sidx + 8] = vc;
    ka = *(const uint4*)&Kg[(size_t)64 * HDIM];
    kc = *(const uint4*)&Kg[(size_t)64 * HDIM + 8];
    va = *(const uint4*)&Vg[64];
    vc = *(const uint4*)&Vg[64 + 8];
    __syncthreads();

#pragma unroll 2
    for (int it = 0; it < 16; ++it) {
        const int cur = it & 1;
        // write tile it+1 into the buffer nobody reads this iteration
        if (it < 15) {
            *(uint4*)&Ks[cur ^ 1][sidx] = ka;
            *(uint4*)&Ks[cur ^ 1][sidx + 8] = kc;
            *(uint4*)&VTs[cur ^ 1][sidx] = va;
            *(uint4*)&VTs[cur ^ 1][sidx + 8] = vc;
        }
        // issue tile it+2 loads; they drain under this iteration's compute
        if (it < 14) {
            ka = *(const uint4*)&Kg[(size_t)(it + 2) * 64 * HDIM];
            kc = *(const uint4*)&Kg[(size_t)(it + 2) * 64 * HDIM + 8];
            va = *(const uint4*)&Vg[(it + 2) * 64];
            vc = *(const uint4*)&Vg[(it + 2) * 64 + 8];
        }
        const u16* Ksc = Ks[cur];
        const u16* Vsc = VTs[cur];

        // S^T[kk][q] = K·Q^T : per wave 64kk x 64q. C/D: col(l16)=q, row(quad*4+r)=kk
        f32x4 sacc[4][4];
#pragma unroll
        for (int mt = 0; mt < 4; ++mt)
#pragma unroll
            for (int nt2 = 0; nt2 < 4; ++nt2) sacc[mt][nt2] = (f32x4){0.f, 0.f, 0.f, 0.f};
#pragma unroll
        for (int ks = 0; ks < 2; ++ks) {
            bf16x8 kf[4];
#pragma unroll
            for (int mt = 0; mt < 4; ++mt)
                kf[mt] = *(const bf16x8*)&Ksc[(mt * 16 + l16) * LPAD + ks * 32 + quad * 8];
#pragma unroll
            for (int mt = 0; mt < 4; ++mt)
#pragma unroll
                for (int nt2 = 0; nt2 < 4; ++nt2)
                    sacc[mt][nt2] = __builtin_amdgcn_mfma_f32_16x16x32_bf16(kf[mt], aq[nt2][ks], sacc[mt][nt2], 0, 0, 0);
        }

        // P = exp2(S) -> bf16 pairs -> quad exchange in-register (VALU, no LDS).
        u32 pq[4][2][4];  // [nt2][ks][c]
#pragma unroll
        for (int nt2 = 0; nt2 < 4; ++nt2) {
            u32 w[4][2];
#pragma unroll
            for (int mt = 0; mt < 4; ++mt) {
                float p0 = __builtin_amdgcn_exp2f(sacc[mt][nt2][0]);
                float p1 = __builtin_amdgcn_exp2f(sacc[mt][nt2][1]);
                float p2 = __builtin_amdgcn_exp2f(sacc[mt][nt2][2]);
                float p3 = __builtin_amdgcn_exp2f(sacc[mt][nt2][3]);
                lsum[nt2] += (p0 + p1) + (p2 + p3);
                w[mt][0] = pack2bf(p0, p1);
                w[mt][1] = pack2bf(p2, p3);
            }
#pragma unroll
            for (int ks = 0; ks < 2; ++ks)
#pragma unroll
                for (int h = 0; h < 2; ++h) {
                    u32 a = w[2 * ks][h], b = w[2 * ks + 1][h];
                    permswap32(a, b);
                    permswap16(a, b);
                    pq[nt2][ks][h] = a;
                    pq[nt2][ks][2 + h] = b;
                }
        }

        // O += P·V : A=P frags (in-register), B=V[d][kk] frags from LDS
#pragma unroll
        for (int ks = 0; ks < 2; ++ks) {
            bf16x8 vf[4];
#pragma unroll
            for (int nt = 0; nt < 4; ++nt)
                vf[nt] = *(const bf16x8*)&Vsc[(nt * 16 + l16) * LPAD + ks * 32 + quad * 8];
#pragma unroll
            for (int mt2 = 0; mt2 < 4; ++mt2) {
                union { u32 u[4]; bf16x8 v; } pf;
                pf.u[0] = pq[mt2][ks][0];
                pf.u[1] = pq[mt2][ks][1];
                pf.u[2] = pq[mt2][ks][2];
                pf.u[3] = pq[mt2][ks][3];
#pragma unroll
                for (int nt = 0; nt < 4; ++nt)
                    o[mt2][nt] = __builtin_amdgcn_mfma_f32_16x16x32_bf16(pf.v, vf[nt], o[mt2][nt], 0, 0, 0);
            }
        }
        // single barrier: separates this iter's buf[cur] reads from next iter's writes,
        // and this iter's buf[cur^1] writes from next iter's reads.
        __syncthreads();
    }

    // complete row sums over the 4 quads (disjoint kk): lane l16 then holds q = nt2*16+l16
#pragma unroll
    for (int nt2 = 0; nt2 < 4; ++nt2) {
        lsum[nt2] += __shfl_xor(lsum[nt2], 16, 64);
        lsum[nt2] += __shfl_xor(lsum[nt2], 32, 64);
    }

    // epilogue: write UNNORMALIZED partial O (bf16) + row sums; gemm_out normalizes.
    const int b = bh >> 4, h = bh & 15;
    u16* dst = hf ? Po1 : Po0;
#pragma unroll
    for (int mt2 = 0; mt2 < 4; ++mt2) {
#pragma unroll
        for (int nt = 0; nt < 4; ++nt) {
            int d = nt * 16 + l16;
#pragma unroll
            for (int r = 0; r < 4; ++r) {
                int q = qblk + mt2 * 16 + quad * 4 + r;
                dst[((size_t)(b * SEQ + q)) * D_MODEL + h * HDIM + d] = f2bf(o[mt2][nt][r]);
            }
        }
    }
    if (quad == 0) {
#pragma unroll
        for (int nt2 = 0; nt2 < 4; ++nt2) {
            int q = qblk + nt2 * 16 + l16;
            Ls[hf * (32 * SEQ) + bh * SEQ + q] = lsum[nt2];
        }
    }
}

// ---------------- output projection: fused combine, software-pipelined A loads ----------
__global__ __launch_bounds__(256) void gemm_out_kernel(
    const u16* __restrict__ Po0, const u16* __restrict__ Po1, const float* __restrict__ Ls,
    const u16* __restrict__ wob, const float* __restrict__ bo, float* __restrict__ dout) {
    __shared__ __align__(16) u16 Asmem[64 * 32];
    __shared__ __align__(16) u16 Bsmem[128 * 32];

    const int tid = threadIdx.x;
    const int lane = tid & 63, wave = tid >> 6;
    const int waveM = wave >> 1, waveN = wave & 1;
    const int quad = lane >> 4, l16 = lane & 15;

    f32x4 acc[2][4];
#pragma unroll
    for (int mt = 0; mt < 2; ++mt)
#pragma unroll
        for (int nt = 0; nt < 4; ++nt) acc[mt][nt] = (f32x4){0.f, 0.f, 0.f, 0.f};

    const int srow = tid >> 2;
    const int scol = (tid & 3) << 3;
    const int q = blockIdx.x * 64 + srow;
    const int b = q >> 11, t = q & (SEQ - 1);
    const size_t arow = (size_t)q * D_MODEL + scol;
    const u16* Bg0 = wob + (size_t)(blockIdx.y * 128 + srow) * D_MODEL + scol;
    const u16* Bg1 = Bg0 + (size_t)64 * D_MODEL;
    u16* Al = Asmem + srow * 32 + scol;
    u16* Bl0 = Bsmem + srow * 32 + scol;
    u16* Bl1 = Bl0 + 64 * 32;

    // precompute 1/l per head for this thread's row (used 2 iters each)
    float rinvh[NHEADS];
    {
        const int bhq0 = b * NHEADS * SEQ + t;
#pragma unroll
        for (int h = 0; h < NHEADS; ++h) {
            int bhq = bhq0 + h * SEQ;
            rinvh[h] = 1.0f / (Ls[bhq] + Ls[32 * SEQ + bhq]);
        }
    }

    // prefetch iter 0's A rows
    uint4 A0 = *(const uint4*)&Po0[arow];
    uint4 A1 = *(const uint4*)&Po1[arow];

    for (int k0 = 0; k0 < D_MODEL; k0 += 32) {
        __syncthreads();
        // A path: fused (Po0+Po1)*rinv -> bf16 -> LDS (uses prefetched regs)
        float rinv = rinvh[(k0 + scol) >> 6];
        const u16* p0 = (const u16*)&A0;
        const u16* p1 = (const u16*)&A1;
        uint4 wv;
        u32* wvp = (u32*)&wv;
#pragma unroll
        for (int j = 0; j < 4; ++j) {
            float s0 = (bf2f(p0[2 * j]) + bf2f(p1[2 * j])) * rinv;
            float s1 = (bf2f(p0[2 * j + 1]) + bf2f(p1[2 * j + 1])) * rinv;
            wvp[j] = pack2bf(s0, s1);
        }
        *(uint4*)Al = wv;
        // B path: async global->LDS
        async_copy16(Bg0 + k0, Bl0);
        async_copy16(Bg1 + k0, Bl1);
        // prefetch next iter's A rows; latency drains with the barrier's vmcnt wait
        if (k0 + 32 < D_MODEL) {
            A0 = *(const uint4*)&Po0[arow + k0 + 32];
            A1 = *(const uint4*)&Po1[arow + k0 + 32];
        }
        __syncthreads();
        bf16x8 af[2], bfr[4];
#pragma unroll
        for (int mt = 0; mt < 2; ++mt)
            af[mt] = *(const bf16x8*)&Asmem[(waveM * 32 + mt * 16 + l16) * 32 + quad * 8];
#pragma unroll
        for (int nt = 0; nt < 4; ++nt)
            bfr[nt] = *(const bf16x8*)&Bsmem[(waveN * 64 + nt * 16 + l16) * 32 + quad * 8];
#pragma unroll
        for (int mt = 0; mt < 2; ++mt)
#pragma unroll
            for (int nt = 0; nt < 4; ++nt)
                acc[mt][nt] = __builtin_amdgcn_mfma_f32_16x16x32_bf16(af[mt], bfr[nt], acc[mt][nt], 0, 0, 0);
    }

    const int gm0 = blockIdx.x * 64 + waveM * 32 + quad * 4;
    const int gn0 = blockIdx.y * 128 + waveN * 64 + l16;

    float bvv[4];
#pragma unroll
    for (int nt = 0; nt < 4; ++nt) bvv[nt] = bo[gn0 + nt * 16];
#pragma unroll
    for (int mt = 0; mt < 2; ++mt)
#pragma unroll
        for (int nt = 0; nt < 4; ++nt)
#pragma unroll
            for (int r = 0; r < 4; ++r)
                dout[(size_t)(gm0 + mt * 16 + r) * D_MODEL + gn0 + nt * 16] = acc[mt][nt][r] + bvv[nt];
}

// ---------------- launch ----------------
extern "C" void kernel_launch(void* const* d_in, const int* in_sizes, int n_in,
                              void* d_out, int out_size, void* d_ws, size_t ws_size,
                              hipStream_t stream) {
    const float* x  = (const float*)d_in[0];
    const float* Wq = (const float*)d_in[1];
    const float* bq = (const float*)d_in[2];
    const float* Wk = (const float*)d_in[3];
    const float* bk = (const float*)d_in[4];
    const float* Wv = (const float*)d_in[5];
    const float* bv = (const float*)d_in[6];
    const float* Wo = (const float*)d_in[7];
    const float* bo = (const float*)d_in[8];
    float* dout = (float*)d_out;

    char* ws = (char*)d_ws;
    size_t off = 0;
    u16* xb  = (u16*)(ws + off); off += (size_t)BT * D_MODEL * 2;        // 8 MB; reused as Po1
    u16* wqb = (u16*)(ws + off); off += (size_t)D_MODEL * D_MODEL * 2;
    u16* wkb = (u16*)(ws + off); off += (size_t)D_MODEL * D_MODEL * 2;
    u16* wvb = (u16*)(ws + off); off += (size_t)D_MODEL * D_MODEL * 2;
    u16* wob = (u16*)(ws + off); off += (size_t)D_MODEL * D_MODEL * 2;
    u16* Qb  = (u16*)(ws + off); off += (size_t)BT * D_MODEL * 2;
    u16* Kb  = (u16*)(ws + off); off += (size_t)BT * D_MODEL * 2;
    u16* VTb = (u16*)(ws + off); off += (size_t)BT * D_MODEL * 2;
    u16* Po0 = (u16*)(ws + off); off += (size_t)BT * D_MODEL * 2;
    float2* csT = (float2*)(ws + off); off += (size_t)SEQ * 32 * 8;      // 0.5 MB
    float* Ls   = (float*)(ws + off); off += (size_t)2 * 32 * SEQ * 4;   // 0.5 MB
    u16* Po1 = xb;  // alias: xb is dead after gemm_qkv

    const int prepN = X4 + 4 * W4 + ROPE_N;
    prep_kernel<<<dim3((prepN + 255) / 256), 256, 0, stream>>>(
        x, Wq, Wk, Wv, Wo, xb, wqb, wkb, wvb, wob, csT);
    gemm_qkv_kernel<<<dim3(BT / 128, D_MODEL / 128, 3), 256, 0, stream>>>(
        xb, wqb, wkb, wvb, bq, bk, bv, csT, Qb, Kb, VTb);
    flash_kernel<<<dim3(SEQ / 256, NBATCH * NHEADS, 2), 256, 0, stream>>>(
        Qb, Kb, VTb, Po0, Po1, Ls);
    gemm_out_kernel<<<dim3(BT / 64, D_MODEL / 128), 256, 0, stream>>>(
        Po0, Po1, Ls, wob, bo, dout);
}